// Round 7
// baseline (222.138 us; speedup 1.0000x reference)
//
#include <hip/hip_runtime.h>
#include <hip/hip_bf16.h>

#define BB 32
#define SS 64
#define DD 256
#define HH 8
#define HDIM 32
#define NSS 65
#define LN_EPS 1e-5f

// ---------------- ws layout (float offsets) ----------------
// T4 layout for descT/VT/varT: elem (d,j) at b*16384 + (d>>2)*256 + j*4 + (d&3)
#define OFF_DESC   0u            // B*S*D = 524288 (row-major)
#define OFF_DESCT  524288u       // T4
#define OFF_U      1048576u      // row-major (be1 + We1a@bg folded)
#define OFF_VT     1572864u      // T4 (We1b@bg folded)
#define OFF_VART   2097152u      // T4 copy of nve[:,1:,:]
#define OFF_VBUF   2621440u      // B*NS*D = 532480 row-major
#define OFF_SQ     3153920u      // 16640
#define OFF_SK     3170560u      // 16640
#define OFF_CTX    3187200u      // 532480
#define OFF_WGT    3719680u      // 65536
#define OFF_WE1AT  3785216u      // 65536
#define OFF_WE1BT  3850752u      // 65536
#define OFF_WVT    3916288u      // 65536
#define OFF_WOT    3981824u      // 65536
#define OFF_CUT    4047360u      // 65536
#define OFF_CVT    4112896u      // 65536
#define OFF_BU     4178432u      // 256
#define OFF_BV     4178688u      // 256
#define OFF_WQF    4178944u      // 2048
#define OFF_WKF    4180992u      // 2048
#define OFF_CVEC   4183040u      // 32
#define OFF_RND    4183072u      // 2048
#define OFF_RNV    4185120u      // 2048
#define OFF_PKG    4187168u      // 512  (lng,lnb interleaved [d][2])
#define OFF_PKM    4187680u      // 2048 (Mf transposed [d][8])
// total 4189728 floats = 16.76 MB

// out[r0+r][o] = bias[o] + sum_k in[r0+r][k]*WT[k][o]; optional T4 copy
__device__ __forceinline__ void gemm16_body(const float* __restrict__ in,
                                            const float* __restrict__ WT,
                                            const float* __restrict__ bias,
                                            float* __restrict__ out,
                                            float* __restrict__ outT,
                                            int r0, int addBias, float* vals) {
    int o = threadIdx.x;
    const float* __restrict__ x = in + (size_t)r0 * DD;   // uniform -> s_load
    float acc[16];
    #pragma unroll
    for (int r = 0; r < 16; ++r) acc[r] = 0.f;
    #pragma unroll 4
    for (int k = 0; k < DD; ++k) {
        float w = WT[(size_t)k * DD + o];
        #pragma unroll
        for (int r = 0; r < 16; ++r)
            acc[r] = fmaf(x[r * DD + k], w, acc[r]);
    }
    float bb = addBias ? bias[o] : 0.f;
    #pragma unroll
    for (int r = 0; r < 16; ++r) vals[r] = acc[r] + bb;
    if (out) {
        #pragma unroll
        for (int r = 0; r < 16; ++r)
            out[(size_t)(r0 + r) * DD + o] = vals[r];
    }
    if (outT) {
        size_t base = (size_t)(r0 >> 6) * 16384 + (size_t)(o >> 2) * 256 + (o & 3);
        int j0 = r0 & 63;
        #pragma unroll
        for (int r = 0; r < 16; ++r)
            outT[base + (size_t)(j0 + r) * 4] = vals[r];
    }
}

// ---- prep_a: 5 transposes + attn folds + PKg (89 blocks) ----
__global__ __launch_bounds__(256) void prep_a(
    const float* __restrict__ Wg, const float* __restrict__ We1,
    const float* __restrict__ Wv, const float* __restrict__ Wo,
    const float* __restrict__ Wq, const float* __restrict__ bq,
    const float* __restrict__ Wk, const float* __restrict__ bk,
    const float* __restrict__ We2, const float* __restrict__ be2,
    const float* __restrict__ Wa, const float* __restrict__ lng,
    const float* __restrict__ lnb,
    float* __restrict__ WgT, float* __restrict__ We1aT, float* __restrict__ We1bT,
    float* __restrict__ WvT, float* __restrict__ WoT,
    float* __restrict__ wqf, float* __restrict__ wkf,
    float* __restrict__ PKg, float* __restrict__ PKm, float* __restrict__ cvec) {
    __shared__ float t[64][65];
    int blk = blockIdx.x;
    if (blk < 80) {
        int which = blk >> 4, t16 = blk & 15;
        const float* src; float* dst; int ld, c0;
        if (which == 0)      { src = Wg;  dst = WgT;   ld = 256; c0 = 0; }
        else if (which == 1) { src = We1; dst = We1aT; ld = 512; c0 = 0; }
        else if (which == 2) { src = We1; dst = We1bT; ld = 512; c0 = 256; }
        else if (which == 3) { src = Wv;  dst = WvT;   ld = 256; c0 = 0; }
        else                 { src = Wo;  dst = WoT;   ld = 256; c0 = 0; }
        int to = t16 & 3, tk = t16 >> 2;
        int tx = threadIdx.x & 63, ty = threadIdx.x >> 6;
        #pragma unroll
        for (int r = ty; r < 64; r += 4)
            t[r][tx] = src[(size_t)(to * 64 + r) * ld + c0 + tk * 64 + tx];
        __syncthreads();
        #pragma unroll
        for (int r = ty; r < 64; r += 4)
            dst[(size_t)(tk * 64 + r) * DD + to * 64 + tx] = t[tx][r];
    } else if (blk < 88) {
        int h = blk - 80, in = threadIdx.x;
        float aq = 0.f, ak = 0.f, ae = 0.f;
        #pragma unroll
        for (int d = 0; d < HDIM; ++d) {
            aq = fmaf(Wq[(h * HDIM + d) * DD + in], Wa[d], aq);
            ak = fmaf(Wk[(h * HDIM + d) * DD + in], Wa[HDIM + d], ak);
            ae = fmaf(We2[(h * HDIM + d) * DD + in], Wa[2 * HDIM + d], ae);
        }
        wqf[h * DD + in] = aq;
        wkf[h * DD + in] = ak;
        PKm[in * HH + h] = ae;
        if (in == 0) {
            float cq = 0.f, ck = 0.f, ce = 0.f;
            for (int d = 0; d < HDIM; ++d) {
                cq = fmaf(bq[h * HDIM + d], Wa[d], cq);
                ck = fmaf(bk[h * HDIM + d], Wa[HDIM + d], ck);
                ce = fmaf(be2[h * HDIM + d], Wa[2 * HDIM + d], ce);
            }
            cvec[h] = cq; cvec[8 + h] = ck; cvec[16 + h] = ce;
        }
    } else {
        int d = threadIdx.x;
        PKg[d * 2] = lng[d];
        PKg[d * 2 + 1] = lnb[d];
    }
}

// ---- prep_b: CuT/CvT GEMMs + bu/bv folds (34 blocks) ----
__global__ __launch_bounds__(256) void prep_b(
    const float* __restrict__ WgT, const float* __restrict__ We1aT,
    const float* __restrict__ We1bT, const float* __restrict__ bg,
    const float* __restrict__ be1,
    float* __restrict__ CuT, float* __restrict__ CvT,
    float* __restrict__ bu, float* __restrict__ bv) {
    float vals[16];
    int blk = blockIdx.x;
    if (blk < 16) gemm16_body(WgT, We1aT, nullptr, CuT, nullptr, blk * 16, 0, vals);
    else if (blk < 32) gemm16_body(WgT, We1bT, nullptr, CvT, nullptr, (blk - 16) * 16, 0, vals);
    else if (blk == 32) {
        int o = threadIdx.x;
        float a = be1[o];
        for (int m = 0; m < DD; ++m) a = fmaf(We1aT[(size_t)m * DD + o], bg[m], a);
        bu[o] = a;
    } else {
        int o = threadIdx.x;
        float a = 0.f;
        for (int m = 0; m < DD; ++m) a = fmaf(We1bT[(size_t)m * DD + o], bg[m], a);
        bv[o] = a;
    }
}

// ---- proj: desc(+T4,+rnd), U, VT4, vbuf, sqsk, rnv, varT4 (804 blocks) ----
__global__ __launch_bounds__(256) void proj_kernel(
    const float* __restrict__ X, const float* __restrict__ nve,
    const float* __restrict__ WgT, const float* __restrict__ CuT,
    const float* __restrict__ CvT, const float* __restrict__ WvT,
    const float* __restrict__ bg, const float* __restrict__ bu,
    const float* __restrict__ bv, const float* __restrict__ bwv,
    const float* __restrict__ wqf, const float* __restrict__ wkf,
    const float* __restrict__ cvec,
    float* __restrict__ desc, float* __restrict__ descT,
    float* __restrict__ U, float* __restrict__ VT,
    float* __restrict__ varT, float* __restrict__ vbuf,
    float* __restrict__ sq, float* __restrict__ sk,
    float* __restrict__ rnd, float* __restrict__ rnv) {
    __shared__ float red[4][16];
    float vals[16];
    int blk = blockIdx.x;
    if (blk < 128) {
        gemm16_body(X, WgT, bg, desc, descT, blk * 16, 1, vals);
        int w = threadIdx.x >> 6, lane = threadIdx.x & 63;
        #pragma unroll
        for (int r = 0; r < 16; ++r) {
            float s2 = vals[r] * vals[r];
            #pragma unroll
            for (int off = 32; off; off >>= 1) s2 += __shfl_xor(s2, off);
            if (lane == 0) red[w][r] = s2;
        }
        __syncthreads();
        if (threadIdx.x < 16) {
            float s = red[0][threadIdx.x] + red[1][threadIdx.x] +
                      red[2][threadIdx.x] + red[3][threadIdx.x];
            rnd[blk * 16 + threadIdx.x] = 1.f / sqrtf(s);
        }
    } else if (blk < 256) {
        gemm16_body(X, CuT, bu, U, nullptr, (blk - 128) * 16, 1, vals);
    } else if (blk < 384) {
        gemm16_body(X, CvT, bv, nullptr, VT, (blk - 256) * 16, 1, vals);
    } else if (blk < 514) {
        gemm16_body(nve, WvT, bwv, vbuf, nullptr, (blk - 384) * 16, 1, vals);
    } else if (blk < 644) {
        int r0 = (blk - 514) * 16;
        int lr = threadIdx.x >> 4, tq = threadIdx.x & 15;
        int g = r0 + lr, b = g / NSS, ii = g % NSS;
        const float* __restrict__ x = nve + (size_t)g * DD;
        const float* __restrict__ wv = ((tq < 8) ? wqf : wkf) + (tq & 7) * DD;
        float acc = 0.f;
        #pragma unroll 8
        for (int k = 0; k < DD; ++k) acc = fmaf(x[k], wv[k], acc);
        int h = tq & 7;
        if (tq < 8) sq[(size_t)(b * HH + h) * NSS + ii] = acc + cvec[h];
        else        sk[(size_t)(b * HH + h) * NSS + ii] = acc + cvec[8 + h];
    } else if (blk < 772) {
        int r0 = (blk - 644) * 16;
        int lr = threadIdx.x >> 4, tq = threadIdx.x & 15;
        int g = r0 + lr, b = g >> 6, s = g & 63;
        const float* __restrict__ x = nve + (size_t)(b * NSS + 1 + s) * DD;
        float ssum = 0.f;
        for (int k = tq; k < DD; k += 16) ssum = fmaf(x[k], x[k], ssum);
        ssum += __shfl_xor(ssum, 1);
        ssum += __shfl_xor(ssum, 2);
        ssum += __shfl_xor(ssum, 4);
        ssum += __shfl_xor(ssum, 8);
        if (tq == 0) rnv[g] = 1.f / sqrtf(ssum);
    } else {
        // varT4: one block per b; thread d, loop j. coalesced reads, scalar stores
        int b = blk - 772;
        int d = threadIdx.x;
        size_t base = (size_t)b * 16384 + (size_t)(d >> 2) * 256 + (d & 3);
        const float* __restrict__ src = nve + ((size_t)b * NSS + 1) * DD + d;
        #pragma unroll 4
        for (int j = 0; j < 64; ++j)
            varT[base + (size_t)j * 4] = src[(size_t)j * DD];
    }
}

// ---- fused adjacency + se + attention: 2 rows x 2 d-halves per block ----
// interior: bid<1024, t = bid>>5 (row pair), b = bid&31 (XCD locality)
// wave w: z=w>>1 row-in-pair, q=w&1 d-half. border: bid-1024 = b.
__global__ __launch_bounds__(256) void se_attn_kernel(
    const float* __restrict__ desc, const float* __restrict__ descT,
    const float* __restrict__ nve,  const float* __restrict__ varT,
    const float* __restrict__ U,    const float* __restrict__ VT,
    const float* __restrict__ vbuf,
    const float* __restrict__ rnd,  const float* __restrict__ rnv,
    const float* __restrict__ sq,   const float* __restrict__ sk,
    const float* __restrict__ PKg,  const float* __restrict__ PKm,
    const float* __restrict__ cvec, const float* __restrict__ ba,
    const float* __restrict__ tb,
    float* __restrict__ aw, float* __restrict__ ctx) {
    __shared__ float SH[4224];   // stat[0..1023] | sep[1024..3071] | awL[3072..4127]
    int bid = blockIdx.x;
    int w = threadIdx.x >> 6, lane = threadIdx.x & 63;
    float bav = ba[0];

    if (bid < 1024) {
        int t = bid >> 5, b = bid & 31;
        int z = w >> 1, q = w & 1;
        int iu = __builtin_amdgcn_readfirstlane(t * 2 + z);   // 0..63
        int i = iu + 1;
        int f0 = q * 32;                                      // 32 f-quads = 128 d
        const float4* __restrict__ dT4  = (const float4*)(descT + (size_t)b * 16384);
        const float4* __restrict__ vrT4 = (const float4*)(varT  + (size_t)b * 16384);
        const float4* __restrict__ vt4  = (const float4*)(VT    + (size_t)b * 16384);
        const float4* __restrict__ di4 = (const float4*)(desc + (size_t)(b * SS + iu) * DD);
        const float4* __restrict__ vi4 = (const float4*)(nve + (size_t)(b * NSS + 1 + iu) * DD);
        const float4* __restrict__ ui4 = (const float4*)(U + (size_t)(b * SS + iu) * DD);

        // ---- fused phase 0+1: gram partials + LN partials (6 streams) ----
        float gd = 0.f, vd = 0.f, ssum = 0.f, s2 = 0.f;
        #pragma unroll 4
        for (int f = 0; f < 32; ++f) {
            int ff = f0 + f;
            float4 a = dT4[ff * 64 + lane];  float4 u1 = di4[ff];
            float4 c = vrT4[ff * 64 + lane]; float4 u2 = vi4[ff];
            float4 v = vt4[ff * 64 + lane];  float4 u = ui4[ff];
            gd = fmaf(a.x, u1.x, gd); gd = fmaf(a.y, u1.y, gd);
            gd = fmaf(a.z, u1.z, gd); gd = fmaf(a.w, u1.w, gd);
            vd = fmaf(c.x, u2.x, vd); vd = fmaf(c.y, u2.y, vd);
            vd = fmaf(c.z, u2.z, vd); vd = fmaf(c.w, u2.w, vd);
            float t0 = v.x + u.x, t1 = v.y + u.y, t2 = v.z + u.z, t3 = v.w + u.w;
            ssum += (t0 + t1) + (t2 + t3);
            s2 = fmaf(t0, t0, s2); s2 = fmaf(t1, t1, s2);
            s2 = fmaf(t2, t2, s2); s2 = fmaf(t3, t3, s2);
        }
        float4* statL = (float4*)SH;
        statL[w * 64 + lane] = make_float4(gd, vd, ssum, s2);
        __syncthreads();
        float4 o = statL[(w ^ 1) * 64 + lane];
        float mu = (ssum + o.z) * (1.f / DD);
        float var = fmaf(-mu, mu, (s2 + o.w) * (1.f / DD));
        float rstd = rsqrtf(var + LN_EPS);
        float gsim = (gd + o.x) * rnd[b * SS + iu] * rnd[b * SS + lane];
        float ssim = (vd + o.y) * rnv[b * SS + iu] * rnv[b * SS + lane];
        bool flag = (gsim + tb[0] > 0.f) && (iu != lane);
        float P = flag ? ssim : 0.f;                 // |P| <= 1, exp safe
        float e = __expf(P);
        float s = e;
        #pragma unroll
        for (int off = 32; off; off >>= 1) s += __shfl_xor(s, off);
        float nav = e / s;

        // ---- phase 2: head-dot partials over this wave's 128 d ----
        float p[HH];
        #pragma unroll
        for (int h = 0; h < HH; ++h) p[h] = 0.f;
        #pragma unroll 2
        for (int f = 0; f < 32; ++f) {
            int ff = f0 + f;
            float4 v = vt4[ff * 64 + lane]; float4 u = ui4[ff];
            const float4* __restrict__ pg = (const float4*)(PKg + 8 * ff);
            float4 pg0 = pg[0], pg1 = pg[1];   // {g0,b0,g1,b1},{g2,b2,g3,b3}
            float tv[4] = {v.x + u.x, v.y + u.y, v.z + u.z, v.w + u.w};
            float gv[4] = {pg0.x, pg0.z, pg1.x, pg1.z};
            float bv_[4] = {pg0.y, pg0.w, pg1.y, pg1.w};
            #pragma unroll
            for (int c2 = 0; c2 < 4; ++c2) {
                const float4* __restrict__ m4 = (const float4*)(PKm + (size_t)(4 * ff + c2) * HH);
                float4 mlo = m4[0], mhi = m4[1];
                float xn = fmaf((tv[c2] - mu) * rstd, gv[c2], bv_[c2]);
                float r = fmaxf(xn, 0.f);
                p[0] = fmaf(r, mlo.x, p[0]); p[1] = fmaf(r, mlo.y, p[1]);
                p[2] = fmaf(r, mlo.z, p[2]); p[3] = fmaf(r, mlo.w, p[3]);
                p[4] = fmaf(r, mhi.x, p[4]); p[5] = fmaf(r, mhi.y, p[5]);
                p[6] = fmaf(r, mhi.z, p[6]); p[7] = fmaf(r, mhi.w, p[7]);
            }
        }
        float* sepL = SH + 1024;
        #pragma unroll
        for (int h = 0; h < HH; ++h) sepL[w * 512 + h * 64 + lane] = p[h];
        __syncthreads();
        #pragma unroll
        for (int h = 0; h < HH; ++h) p[h] += sepL[(w ^ 1) * 512 + h * 64 + lane];
        // static head selection: this wave handles heads q*4..q*4+3
        float psel[4];
        #pragma unroll
        for (int hh = 0; hh < 4; ++hh) psel[hh] = q ? p[4 + hh] : p[hh];

        // ---- phase 3a: softmax for 4 heads -> aw + LDS ----
        float* awL = SH + 3072 + z * 528;   // [8][66] per row
        #pragma unroll
        for (int hh = 0; hh < 4; ++hh) {
            int h = q * 4 + hh;
            float sev = nav * (psel[hh] + cvec[16 + h]);
            float sc = sq[(size_t)(b * HH + h) * NSS + i] +
                       sk[(size_t)(b * HH + h) * NSS + 1 + lane] + sev + bav;
            float m = sc;
            #pragma unroll
            for (int off = 32; off; off >>= 1) m = fmaxf(m, __shfl_xor(m, off));
            float e2 = __expf(sc - m);
            float tot = e2;
            #pragma unroll
            for (int off = 32; off; off >>= 1) tot += __shfl_xor(tot, off);
            float aval = e2 / tot;
            float* awrow = aw + ((size_t)(b * HH + h) * NSS + i) * NSS;
            awrow[1 + lane] = aval;
            if (lane == 0) awrow[0] = 0.f;
            awL[h * 66 + lane] = aval;
        }
        __syncthreads();

        // ---- phase 3b: ctx, lane pair owns d-quad qd, j split by parity ----
        int qd = q * 32 + (lane & 31);      // 0..63 quad of this row's d
        int head = qd >> 3;
        int jh = lane >> 5;
        const float* __restrict__ awh = SH + 3072 + z * 528 + head * 66;
        const float4* __restrict__ vb4 = (const float4*)(vbuf + ((size_t)b * NSS + 1) * DD);
        float cx = 0.f, cy = 0.f, cz = 0.f, cw = 0.f;
        #pragma unroll 8
        for (int j2 = 0; j2 < 32; ++j2) {
            int j = j2 * 2 + jh;
            float a = awh[j];
            float4 v = vb4[(size_t)j * 64 + qd];
            cx = fmaf(a, v.x, cx); cy = fmaf(a, v.y, cy);
            cz = fmaf(a, v.z, cz); cw = fmaf(a, v.w, cw);
        }
        cx += __shfl_xor(cx, 32); cy += __shfl_xor(cy, 32);
        cz += __shfl_xor(cz, 32); cw += __shfl_xor(cw, 32);
        if (lane < 32)
            *(float4*)(ctx + ((size_t)(b * NSS) + i) * DD + qd * 4) =
                make_float4(cx, cy, cz, cw);
    } else {
        // ---- border row i=0: h_0j = U[j]+V[j]; na = 1 ----
        int b = bid - 1024;
        float* tile = SH;   // [64][65]
        int dloc = lane & 31, jh = lane >> 5;
        float ss = 0.f, s2 = 0.f;
        for (int c = 0; c < 4; ++c) {
            for (int jr = w; jr < 64; jr += 4)
                tile[jr * 65 + lane] = U[(size_t)(b * SS + jr) * DD + c * 64 + lane];
            __syncthreads();
            #pragma unroll 8
            for (int dd = 0; dd < 64; ++dd) {
                int d = c * 64 + dd;
                float u = tile[lane * 65 + dd];
                float v = VT[(size_t)b * 16384 + (size_t)(d >> 2) * 256 + lane * 4 + (d & 3)];
                float t2 = u + v; ss += t2; s2 = fmaf(t2, t2, s2);
            }
            __syncthreads();
        }
        float mu = ss * (1.f / DD);
        float va = fmaf(-mu, mu, s2 * (1.f / DD));
        float rstd = rsqrtf(va + LN_EPS);
        float p[HH];
        #pragma unroll
        for (int h = 0; h < HH; ++h) p[h] = 0.f;
        for (int c = 0; c < 4; ++c) {
            for (int jr = w; jr < 64; jr += 4)
                tile[jr * 65 + lane] = U[(size_t)(b * SS + jr) * DD + c * 64 + lane];
            __syncthreads();
            #pragma unroll 4
            for (int dd = 0; dd < 64; ++dd) {
                int d = c * 64 + dd;
                float u = tile[lane * 65 + dd];
                float v = VT[(size_t)b * 16384 + (size_t)(d >> 2) * 256 + lane * 4 + (d & 3)];
                float t2 = u + v;
                float rv = fmaxf(fmaf((t2 - mu) * rstd, PKg[d * 2], PKg[d * 2 + 1]), 0.f);
                const float* __restrict__ m8 = PKm + (size_t)d * HH;
                #pragma unroll
                for (int h = 0; h < HH; ++h) p[h] = fmaf(rv, m8[h], p[h]);
            }
            __syncthreads();
        }
        float sel0 = 0.f, sel1 = 0.f;
        #pragma unroll
        for (int h = 0; h < HH; ++h) {
            if (h == w * 2)     sel0 = p[h];
            if (h == w * 2 + 1) sel1 = p[h];
        }
        #pragma unroll
        for (int q2 = 0; q2 < 2; ++q2) {
            int h = w * 2 + q2;
            float dot = q2 ? sel1 : sel0;
            float sev = dot + cvec[16 + h];
            float skh = sk[(size_t)(b * HH + h) * NSS + 1 + lane];
            float sc = sq[(size_t)(b * HH + h) * NSS] + skh + sev + bav;
            float m = sc;
            #pragma unroll
            for (int off = 32; off; off >>= 1) m = fmaxf(m, __shfl_xor(m, off));
            float e = __expf(sc - m), s = e;
            #pragma unroll
            for (int off = 32; off; off >>= 1) s += __shfl_xor(s, off);
            float aval = e / s;
            float* awrow = aw + ((size_t)(b * HH + h) * NSS) * NSS;
            awrow[1 + lane] = aval;
            if (lane == 0) awrow[0] = 0.f;
            float acc = 0.f;
            #pragma unroll
            for (int j2 = 0; j2 < 32; ++j2) {
                int jj = j2 * 2 + jh;
                float a = __shfl(aval, jj);
                acc = fmaf(a, vbuf[((size_t)(b * NSS) + 1 + jj) * DD + h * HDIM + dloc], acc);
            }
            acc += __shfl_xor(acc, 32);
            if (lane < 32)
                ctx[(size_t)(b * NSS) * DD + h * HDIM + dloc] = acc;
        }
    }
}

// ---- out = ctx @ WoT + bo (130 blocks) ----
__global__ __launch_bounds__(256) void outgemm_kernel(
    const float* __restrict__ ctx, const float* __restrict__ WoT,
    const float* __restrict__ bo, float* __restrict__ out) {
    float vals[16];
    gemm16_body(ctx, WoT, bo, out, nullptr, blockIdx.x * 16, 1, vals);
}

extern "C" void kernel_launch(void* const* d_in, const int* in_sizes, int n_in,
                              void* d_out, int out_size, void* d_ws, size_t ws_size,
                              hipStream_t stream) {
    const float* desc_emb = (const float*)d_in[0];
    const float* nve      = (const float*)d_in[1];
    const float* Wg  = (const float*)d_in[2];
    const float* bg  = (const float*)d_in[3];
    const float* Wq  = (const float*)d_in[4];
    const float* bq  = (const float*)d_in[5];
    const float* Wk  = (const float*)d_in[6];
    const float* bk  = (const float*)d_in[7];
    const float* Wv  = (const float*)d_in[8];
    const float* bv_in = (const float*)d_in[9];
    const float* We1 = (const float*)d_in[10];
    const float* be1 = (const float*)d_in[11];
    const float* lng = (const float*)d_in[12];
    const float* lnb = (const float*)d_in[13];
    const float* We2 = (const float*)d_in[14];
    const float* be2 = (const float*)d_in[15];
    const float* Wa  = (const float*)d_in[16];
    const float* ba  = (const float*)d_in[17];
    const float* Wo  = (const float*)d_in[18];
    const float* bo  = (const float*)d_in[19];
    const float* tb  = (const float*)d_in[20];

    float* ws    = (float*)d_ws;
    float* desc  = ws + OFF_DESC;
    float* descT = ws + OFF_DESCT;
    float* U     = ws + OFF_U;
    float* VT    = ws + OFF_VT;
    float* varT  = ws + OFF_VART;
    float* vbuf  = ws + OFF_VBUF;
    float* sq    = ws + OFF_SQ;
    float* sk    = ws + OFF_SK;
    float* ctx   = ws + OFF_CTX;
    float* WgT   = ws + OFF_WGT;
    float* We1aT = ws + OFF_WE1AT;
    float* We1bT = ws + OFF_WE1BT;
    float* WvT   = ws + OFF_WVT;
    float* WoT   = ws + OFF_WOT;
    float* CuT   = ws + OFF_CUT;
    float* CvT   = ws + OFF_CVT;
    float* bu    = ws + OFF_BU;
    float* bv    = ws + OFF_BV;
    float* wqf   = ws + OFF_WQF;
    float* wkf   = ws + OFF_WKF;
    float* cvec  = ws + OFF_CVEC;
    float* rnd   = ws + OFF_RND;
    float* rnv   = ws + OFF_RNV;
    float* PKg   = ws + OFF_PKG;
    float* PKm   = ws + OFF_PKM;

    float* out = (float*)d_out;                  // [B][NS][D]
    float* aw  = out + (size_t)BB * NSS * DD;    // [B][H][NS][NS]

    prep_a<<<89, 256, 0, stream>>>(Wg, We1, Wv, Wo, Wq, bq, Wk, bk, We2, be2,
                                   Wa, lng, lnb,
                                   WgT, We1aT, We1bT, WvT, WoT,
                                   wqf, wkf, PKg, PKm, cvec);
    prep_b<<<34, 256, 0, stream>>>(WgT, We1aT, We1bT, bg, be1, CuT, CvT, bu, bv);
    proj_kernel<<<804, 256, 0, stream>>>(desc_emb, nve, WgT, CuT, CvT, WvT,
                                         bg, bu, bv, bv_in, wqf, wkf, cvec,
                                         desc, descT, U, VT, varT, vbuf,
                                         sq, sk, rnd, rnv);
    se_attn_kernel<<<1056, 256, 0, stream>>>(desc, descT, nve, varT, U, VT,
                                             vbuf, rnd, rnv, sq, sk,
                                             PKg, PKm, cvec, ba, tb, aw, ctx);
    outgemm_kernel<<<130, 256, 0, stream>>>(ctx, WoT, bo, out);
}

// Round 9
// 145.117 us; speedup vs baseline: 1.5308x; 1.5308x over previous
//
#include <hip/hip_runtime.h>
#include <hip/hip_bf16.h>

#define BB 32
#define SS 64
#define DD 256
#define HH 8
#define HDIM 32
#define NSS 65
#define LN_EPS 1e-5f

// ---------------- ws layout (float offsets) ----------------
// T4 layout for descT/VT/varT: elem (d,j) at b*16384 + (d>>2)*256 + j*4 + (d&3)
#define OFF_DESC   0u            // B*S*D = 524288 (row-major)
#define OFF_DESCT  524288u       // T4
#define OFF_U      1048576u      // row-major (be1 + We1a@bg folded)
#define OFF_VT     1572864u      // T4 (We1b@bg folded)
#define OFF_VART   2097152u      // T4 copy of nve[:,1:,:]
#define OFF_VBUF   2621440u      // B*NS*D = 532480 row-major
#define OFF_SQ     3153920u      // 16640
#define OFF_SK     3170560u      // 16640
#define OFF_CTX    3187200u      // 532480
#define OFF_WGT    3719680u      // 65536
#define OFF_WE1AT  3785216u      // 65536
#define OFF_WE1BT  3850752u      // 65536
#define OFF_WVT    3916288u      // 65536
#define OFF_WOT    3981824u      // 65536
#define OFF_CUT    4047360u      // 65536
#define OFF_CVT    4112896u      // 65536
#define OFF_BU     4178432u      // 256
#define OFF_BV     4178688u      // 256
#define OFF_WQF    4178944u      // 2048
#define OFF_WKF    4180992u      // 2048
#define OFF_CVEC   4183040u      // 32
#define OFF_RND    4183072u      // 2048
#define OFF_RNV    4185120u      // 2048
#define OFF_PKG    4187168u      // 512  (lng,lnb interleaved [d][2])
#define OFF_PKM    4187680u      // 2048 (Mf transposed [d][8])
// total 4189728 floats = 16.76 MB

// out[r0+r][o] = bias[o] + sum_k in[r0+r][k]*WT[k][o]; optional T4 copy
// NOTE: T4 rows are 4 floats apart -> outT stores MUST stay scalar (stride-4
// scatter). Vectorizing them (round 8) corrupts 3 of 4 rows.
template <int R>
__device__ __forceinline__ void gemmR_body(const float* __restrict__ in,
                                           const float* __restrict__ WT,
                                           const float* __restrict__ bias,
                                           float* __restrict__ out,
                                           float* __restrict__ outT,
                                           int r0, int addBias, float* vals) {
    int o = threadIdx.x;
    const float* __restrict__ x = in + (size_t)r0 * DD;   // uniform -> s_load
    float acc[R];
    #pragma unroll
    for (int r = 0; r < R; ++r) acc[r] = 0.f;
    #pragma unroll 4
    for (int k = 0; k < DD; ++k) {
        float w = WT[(size_t)k * DD + o];
        #pragma unroll
        for (int r = 0; r < R; ++r)
            acc[r] = fmaf(x[r * DD + k], w, acc[r]);
    }
    float bb = addBias ? bias[o] : 0.f;
    #pragma unroll
    for (int r = 0; r < R; ++r) vals[r] = acc[r] + bb;
    if (out) {
        #pragma unroll
        for (int r = 0; r < R; ++r)
            out[(size_t)(r0 + r) * DD + o] = vals[r];
    }
    if (outT) {
        size_t base = (size_t)(r0 >> 6) * 16384 + (size_t)(o >> 2) * 256 + (o & 3);
        int j0 = r0 & 63;
        #pragma unroll
        for (int r = 0; r < R; ++r)
            outT[base + (size_t)(j0 + r) * 4] = vals[r];
    }
}

// ---- prep_a: 5 transposes + attn folds + PKg (89 blocks) ----
__global__ __launch_bounds__(256) void prep_a(
    const float* __restrict__ Wg, const float* __restrict__ We1,
    const float* __restrict__ Wv, const float* __restrict__ Wo,
    const float* __restrict__ Wq, const float* __restrict__ bq,
    const float* __restrict__ Wk, const float* __restrict__ bk,
    const float* __restrict__ We2, const float* __restrict__ be2,
    const float* __restrict__ Wa, const float* __restrict__ lng,
    const float* __restrict__ lnb,
    float* __restrict__ WgT, float* __restrict__ We1aT, float* __restrict__ We1bT,
    float* __restrict__ WvT, float* __restrict__ WoT,
    float* __restrict__ wqf, float* __restrict__ wkf,
    float* __restrict__ PKg, float* __restrict__ PKm, float* __restrict__ cvec) {
    __shared__ float t[64][65];
    int blk = blockIdx.x;
    if (blk < 80) {
        int which = blk >> 4, t16 = blk & 15;
        const float* src; float* dst; int ld, c0;
        if (which == 0)      { src = Wg;  dst = WgT;   ld = 256; c0 = 0; }
        else if (which == 1) { src = We1; dst = We1aT; ld = 512; c0 = 0; }
        else if (which == 2) { src = We1; dst = We1bT; ld = 512; c0 = 256; }
        else if (which == 3) { src = Wv;  dst = WvT;   ld = 256; c0 = 0; }
        else                 { src = Wo;  dst = WoT;   ld = 256; c0 = 0; }
        int to = t16 & 3, tk = t16 >> 2;
        int tx = threadIdx.x & 63, ty = threadIdx.x >> 6;
        #pragma unroll
        for (int r = ty; r < 64; r += 4)
            t[r][tx] = src[(size_t)(to * 64 + r) * ld + c0 + tk * 64 + tx];
        __syncthreads();
        #pragma unroll
        for (int r = ty; r < 64; r += 4)
            dst[(size_t)(tk * 64 + r) * DD + to * 64 + tx] = t[tx][r];
    } else if (blk < 88) {
        int h = blk - 80, in = threadIdx.x;
        float aq = 0.f, ak = 0.f, ae = 0.f;
        #pragma unroll
        for (int d = 0; d < HDIM; ++d) {
            aq = fmaf(Wq[(h * HDIM + d) * DD + in], Wa[d], aq);
            ak = fmaf(Wk[(h * HDIM + d) * DD + in], Wa[HDIM + d], ak);
            ae = fmaf(We2[(h * HDIM + d) * DD + in], Wa[2 * HDIM + d], ae);
        }
        wqf[h * DD + in] = aq;
        wkf[h * DD + in] = ak;
        PKm[in * HH + h] = ae;
        if (in == 0) {
            float cq = 0.f, ck = 0.f, ce = 0.f;
            for (int d = 0; d < HDIM; ++d) {
                cq = fmaf(bq[h * HDIM + d], Wa[d], cq);
                ck = fmaf(bk[h * HDIM + d], Wa[HDIM + d], ck);
                ce = fmaf(be2[h * HDIM + d], Wa[2 * HDIM + d], ce);
            }
            cvec[h] = cq; cvec[8 + h] = ck; cvec[16 + h] = ce;
        }
    } else {
        int d = threadIdx.x;
        PKg[d * 2] = lng[d];
        PKg[d * 2 + 1] = lnb[d];
    }
}

// ---- prep_b: CuT/CvT GEMMs + bu/bv folds (34 blocks) ----
__global__ __launch_bounds__(256) void prep_b(
    const float* __restrict__ WgT, const float* __restrict__ We1aT,
    const float* __restrict__ We1bT, const float* __restrict__ bg,
    const float* __restrict__ be1,
    float* __restrict__ CuT, float* __restrict__ CvT,
    float* __restrict__ bu, float* __restrict__ bv) {
    float vals[16];
    int blk = blockIdx.x;
    if (blk < 16) gemmR_body<16>(WgT, We1aT, nullptr, CuT, nullptr, blk * 16, 0, vals);
    else if (blk < 32) gemmR_body<16>(WgT, We1bT, nullptr, CvT, nullptr, (blk - 16) * 16, 0, vals);
    else if (blk == 32) {
        int o = threadIdx.x;
        float a = be1[o];
        for (int m = 0; m < DD; ++m) a = fmaf(We1aT[(size_t)m * DD + o], bg[m], a);
        bu[o] = a;
    } else {
        int o = threadIdx.x;
        float a = 0.f;
        for (int m = 0; m < DD; ++m) a = fmaf(We1bT[(size_t)m * DD + o], bg[m], a);
        bv[o] = a;
    }
}

// ---- proj: desc(+T4,+rnd), U, VT4, vbuf, sqsk, rnv, varT4 (1318 blocks, R=8) ----
__global__ __launch_bounds__(256) void proj_kernel(
    const float* __restrict__ X, const float* __restrict__ nve,
    const float* __restrict__ WgT, const float* __restrict__ CuT,
    const float* __restrict__ CvT, const float* __restrict__ WvT,
    const float* __restrict__ bg, const float* __restrict__ bu,
    const float* __restrict__ bv, const float* __restrict__ bwv,
    const float* __restrict__ wqf, const float* __restrict__ wkf,
    const float* __restrict__ cvec,
    float* __restrict__ desc, float* __restrict__ descT,
    float* __restrict__ U, float* __restrict__ VT,
    float* __restrict__ varT, float* __restrict__ vbuf,
    float* __restrict__ sq, float* __restrict__ sk,
    float* __restrict__ rnd, float* __restrict__ rnv) {
    __shared__ float red[4][8];
    float vals[8];
    int blk = blockIdx.x;
    if (blk < 256) {
        gemmR_body<8>(X, WgT, bg, desc, descT, blk * 8, 1, vals);
        int w = threadIdx.x >> 6, lane = threadIdx.x & 63;
        #pragma unroll
        for (int r = 0; r < 8; ++r) {
            float s2 = vals[r] * vals[r];
            #pragma unroll
            for (int off = 32; off; off >>= 1) s2 += __shfl_xor(s2, off);
            if (lane == 0) red[w][r] = s2;
        }
        __syncthreads();
        if (threadIdx.x < 8) {
            float s = red[0][threadIdx.x] + red[1][threadIdx.x] +
                      red[2][threadIdx.x] + red[3][threadIdx.x];
            rnd[blk * 8 + threadIdx.x] = 1.f / sqrtf(s);
        }
    } else if (blk < 512) {
        gemmR_body<8>(X, CuT, bu, U, nullptr, (blk - 256) * 8, 1, vals);
    } else if (blk < 768) {
        gemmR_body<8>(X, CvT, bv, nullptr, VT, (blk - 512) * 8, 1, vals);
    } else if (blk < 1028) {
        gemmR_body<8>(nve, WvT, bwv, vbuf, nullptr, (blk - 768) * 8, 1, vals);
    } else if (blk < 1158) {
        int r0 = (blk - 1028) * 16;
        int lr = threadIdx.x >> 4, tq = threadIdx.x & 15;
        int g = r0 + lr, b = g / NSS, ii = g % NSS;
        const float* __restrict__ x = nve + (size_t)g * DD;
        const float* __restrict__ wv = ((tq < 8) ? wqf : wkf) + (tq & 7) * DD;
        float acc = 0.f;
        #pragma unroll 8
        for (int k = 0; k < DD; ++k) acc = fmaf(x[k], wv[k], acc);
        int h = tq & 7;
        if (tq < 8) sq[(size_t)(b * HH + h) * NSS + ii] = acc + cvec[h];
        else        sk[(size_t)(b * HH + h) * NSS + ii] = acc + cvec[8 + h];
    } else if (blk < 1286) {
        int r0 = (blk - 1158) * 16;
        int lr = threadIdx.x >> 4, tq = threadIdx.x & 15;
        int g = r0 + lr, b = g >> 6, s = g & 63;
        const float* __restrict__ x = nve + (size_t)(b * NSS + 1 + s) * DD;
        float ssum = 0.f;
        for (int k = tq; k < DD; k += 16) ssum = fmaf(x[k], x[k], ssum);
        ssum += __shfl_xor(ssum, 1);
        ssum += __shfl_xor(ssum, 2);
        ssum += __shfl_xor(ssum, 4);
        ssum += __shfl_xor(ssum, 8);
        if (tq == 0) rnv[g] = 1.f / sqrtf(ssum);
    } else {
        // varT4: one block per b; thread d, loop j. coalesced reads, scalar stores
        int b = blk - 1286;
        int d = threadIdx.x;
        size_t base = (size_t)b * 16384 + (size_t)(d >> 2) * 256 + (d & 3);
        const float* __restrict__ src = nve + ((size_t)b * NSS + 1) * DD + d;
        #pragma unroll 4
        for (int j = 0; j < 64; ++j)
            varT[base + (size_t)j * 4] = src[(size_t)j * DD];
    }
}

// ---- fused adjacency + se + attention: 1 full row per wave, NO barriers ----
// grid 544: bid -> (t = bid>>5, b = bid&31)  [XCD locality: same b -> same L2]
__global__ __launch_bounds__(256) void se_attn_kernel(
    const float* __restrict__ desc, const float* __restrict__ descT,
    const float* __restrict__ nve,  const float* __restrict__ varT,
    const float* __restrict__ U,    const float* __restrict__ VT,
    const float* __restrict__ vbuf,
    const float* __restrict__ rnd,  const float* __restrict__ rnv,
    const float* __restrict__ sq,   const float* __restrict__ sk,
    const float* __restrict__ PKg,  const float* __restrict__ PKm,
    const float* __restrict__ cvec, const float* __restrict__ ba,
    const float* __restrict__ tb,
    float* __restrict__ aw, float* __restrict__ ctx) {
    __shared__ float SH[4224];   // interior: awL[4][8][66]; border: tile[64][65]
    int t = blockIdx.x >> 5, b = blockIdx.x & 31;
    int w = threadIdx.x >> 6, lane = threadIdx.x & 63;
    float bav = ba[0];

    if (t < 16) {
        int iu = __builtin_amdgcn_readfirstlane(t * 4 + w);   // 0..63
        int i = iu + 1;
        const float4* __restrict__ dT4  = (const float4*)(descT + (size_t)b * 16384);
        const float4* __restrict__ vrT4 = (const float4*)(varT  + (size_t)b * 16384);
        const float4* __restrict__ vt4  = (const float4*)(VT    + (size_t)b * 16384);
        const float4* __restrict__ di4 = (const float4*)(desc + (size_t)(b * SS + iu) * DD);
        const float4* __restrict__ vi4 = (const float4*)(nve + (size_t)(b * NSS + 1 + iu) * DD);
        const float4* __restrict__ ui4 = (const float4*)(U + (size_t)(b * SS + iu) * DD);

        // ---- fused phase 0+1: gram dots + LN stats, 6 streams, no barriers ----
        float gd = 0.f, vd = 0.f, ssum = 0.f, s2 = 0.f;
        #pragma unroll 4
        for (int f = 0; f < 64; ++f) {
            float4 a = dT4[f * 64 + lane];  float4 u1 = di4[f];
            float4 c = vrT4[f * 64 + lane]; float4 u2 = vi4[f];
            float4 v = vt4[f * 64 + lane];  float4 u = ui4[f];
            gd = fmaf(a.x, u1.x, gd); gd = fmaf(a.y, u1.y, gd);
            gd = fmaf(a.z, u1.z, gd); gd = fmaf(a.w, u1.w, gd);
            vd = fmaf(c.x, u2.x, vd); vd = fmaf(c.y, u2.y, vd);
            vd = fmaf(c.z, u2.z, vd); vd = fmaf(c.w, u2.w, vd);
            float t0 = v.x + u.x, t1 = v.y + u.y, t2 = v.z + u.z, t3 = v.w + u.w;
            ssum += (t0 + t1) + (t2 + t3);
            s2 = fmaf(t0, t0, s2); s2 = fmaf(t1, t1, s2);
            s2 = fmaf(t2, t2, s2); s2 = fmaf(t3, t3, s2);
        }
        float gsim = gd * rnd[b * SS + iu] * rnd[b * SS + lane];
        float ssim = vd * rnv[b * SS + iu] * rnv[b * SS + lane];
        bool flag = (gsim + tb[0] > 0.f) && (iu != lane);
        float P = flag ? ssim : 0.f;                 // |P| <= 1, exp safe
        float e = __expf(P);
        float s = e;
        #pragma unroll
        for (int off = 32; off; off >>= 1) s += __shfl_xor(s, off);
        float nav = e / s;
        float mu = ssum * (1.f / DD);
        float var = fmaf(-mu, mu, s2 * (1.f / DD));
        float rstd = rsqrtf(var + LN_EPS);

        // ---- phase 2: head dots (vt4/ui4 re-read, L1/L2-hot) ----
        float p[HH];
        #pragma unroll
        for (int h = 0; h < HH; ++h) p[h] = 0.f;
        #pragma unroll 2
        for (int f = 0; f < 64; ++f) {
            float4 v = vt4[f * 64 + lane]; float4 u = ui4[f];
            const float4* __restrict__ pg = (const float4*)(PKg + 8 * f);
            float4 pg0 = pg[0], pg1 = pg[1];   // {g0,b0,g1,b1},{g2,b2,g3,b3}
            float tv[4] = {v.x + u.x, v.y + u.y, v.z + u.z, v.w + u.w};
            float gv[4] = {pg0.x, pg0.z, pg1.x, pg1.z};
            float bv_[4] = {pg0.y, pg0.w, pg1.y, pg1.w};
            #pragma unroll
            for (int c = 0; c < 4; ++c) {
                const float4* __restrict__ m4 = (const float4*)(PKm + (size_t)(4 * f + c) * HH);
                float4 mlo = m4[0], mhi = m4[1];
                float xn = fmaf((tv[c] - mu) * rstd, gv[c], bv_[c]);
                float r = fmaxf(xn, 0.f);
                p[0] = fmaf(r, mlo.x, p[0]); p[1] = fmaf(r, mlo.y, p[1]);
                p[2] = fmaf(r, mlo.z, p[2]); p[3] = fmaf(r, mlo.w, p[3]);
                p[4] = fmaf(r, mhi.x, p[4]); p[5] = fmaf(r, mhi.y, p[5]);
                p[6] = fmaf(r, mhi.z, p[6]); p[7] = fmaf(r, mhi.w, p[7]);
            }
        }

        // ---- phase 3a: per-head softmax -> aw + LDS (within-wave, no barrier) ----
        float* awL = SH + w * 528;   // [8][66]
        #pragma unroll
        for (int h = 0; h < HH; ++h) {
            float sev = nav * (p[h] + cvec[16 + h]);
            float sc = sq[(size_t)(b * HH + h) * NSS + i] +
                       sk[(size_t)(b * HH + h) * NSS + 1 + lane] + sev + bav;
            float m = sc;
            #pragma unroll
            for (int off = 32; off; off >>= 1) m = fmaxf(m, __shfl_xor(m, off));
            float e2 = __expf(sc - m);
            float tot = e2;
            #pragma unroll
            for (int off = 32; off; off >>= 1) tot += __shfl_xor(tot, off);
            float aval = e2 / tot;
            float* awrow = aw + ((size_t)(b * HH + h) * NSS + i) * NSS;
            awrow[1 + lane] = aval;
            if (lane == 0) awrow[0] = 0.f;
            awL[h * 66 + lane] = aval;
        }
        // ---- phase 3b: ctx, lane owns d-quad (d=4*lane), head = lane>>3 ----
        const float* __restrict__ awh = awL + (lane >> 3) * 66;
        const float4* __restrict__ vb4 = (const float4*)(vbuf + ((size_t)b * NSS + 1) * DD);
        float cx = 0.f, cy = 0.f, cz = 0.f, cw = 0.f;
        #pragma unroll 4
        for (int j = 0; j < 64; ++j) {
            float a = awh[j];
            float4 v = vb4[(size_t)j * 64 + lane];
            cx = fmaf(a, v.x, cx); cy = fmaf(a, v.y, cy);
            cz = fmaf(a, v.z, cz); cw = fmaf(a, v.w, cw);
        }
        *(float4*)(ctx + ((size_t)(b * NSS) + i) * DD + 4 * lane) =
            make_float4(cx, cy, cz, cw);
    } else {
        // ---- border row i=0: h_0j = U[j]+V[j]; na = 1 ----
        float* tile = SH;   // [64][65]
        int dloc = lane & 31, jh = lane >> 5;
        float ss = 0.f, s2 = 0.f;
        for (int c = 0; c < 4; ++c) {
            for (int jr = w; jr < 64; jr += 4)
                tile[jr * 65 + lane] = U[(size_t)(b * SS + jr) * DD + c * 64 + lane];
            __syncthreads();
            #pragma unroll 8
            for (int dd = 0; dd < 64; ++dd) {
                int d = c * 64 + dd;
                float u = tile[lane * 65 + dd];
                float v = VT[(size_t)b * 16384 + (size_t)(d >> 2) * 256 + lane * 4 + (d & 3)];
                float t2 = u + v; ss += t2; s2 = fmaf(t2, t2, s2);
            }
            __syncthreads();
        }
        float mu = ss * (1.f / DD);
        float va = fmaf(-mu, mu, s2 * (1.f / DD));
        float rstd = rsqrtf(va + LN_EPS);
        float p[HH];
        #pragma unroll
        for (int h = 0; h < HH; ++h) p[h] = 0.f;
        for (int c = 0; c < 4; ++c) {
            for (int jr = w; jr < 64; jr += 4)
                tile[jr * 65 + lane] = U[(size_t)(b * SS + jr) * DD + c * 64 + lane];
            __syncthreads();
            #pragma unroll 4
            for (int dd = 0; dd < 64; ++dd) {
                int d = c * 64 + dd;
                float u = tile[lane * 65 + dd];
                float v = VT[(size_t)b * 16384 + (size_t)(d >> 2) * 256 + lane * 4 + (d & 3)];
                float t2 = u + v;
                float rv = fmaxf(fmaf((t2 - mu) * rstd, PKg[d * 2], PKg[d * 2 + 1]), 0.f);
                const float* __restrict__ m8 = PKm + (size_t)d * HH;
                #pragma unroll
                for (int h = 0; h < HH; ++h) p[h] = fmaf(rv, m8[h], p[h]);
            }
            __syncthreads();
        }
        float sel0 = 0.f, sel1 = 0.f;
        #pragma unroll
        for (int h = 0; h < HH; ++h) {
            if (h == w * 2)     sel0 = p[h];
            if (h == w * 2 + 1) sel1 = p[h];
        }
        #pragma unroll
        for (int q = 0; q < 2; ++q) {
            int h = w * 2 + q;
            float dot = q ? sel1 : sel0;
            float sev = dot + cvec[16 + h];
            float skh = sk[(size_t)(b * HH + h) * NSS + 1 + lane];
            float sc = sq[(size_t)(b * HH + h) * NSS] + skh + sev + bav;
            float m = sc;
            #pragma unroll
            for (int off = 32; off; off >>= 1) m = fmaxf(m, __shfl_xor(m, off));
            float e = __expf(sc - m), s = e;
            #pragma unroll
            for (int off = 32; off; off >>= 1) s += __shfl_xor(s, off);
            float aval = e / s;
            float* awrow = aw + ((size_t)(b * HH + h) * NSS) * NSS;
            awrow[1 + lane] = aval;
            if (lane == 0) awrow[0] = 0.f;
            float acc = 0.f;
            #pragma unroll
            for (int j2 = 0; j2 < 32; ++j2) {
                int jj = j2 * 2 + jh;
                float a = __shfl(aval, jj);
                acc = fmaf(a, vbuf[((size_t)(b * NSS) + 1 + jj) * DD + h * HDIM + dloc], acc);
            }
            acc += __shfl_xor(acc, 32);
            if (lane < 32)
                ctx[(size_t)(b * NSS) * DD + h * HDIM + dloc] = acc;
        }
    }
}

// ---- out = ctx @ WoT + bo (260 blocks, R=8) ----
__global__ __launch_bounds__(256) void outgemm_kernel(
    const float* __restrict__ ctx, const float* __restrict__ WoT,
    const float* __restrict__ bo, float* __restrict__ out) {
    float vals[8];
    gemmR_body<8>(ctx, WoT, bo, out, nullptr, blockIdx.x * 8, 1, vals);
}

extern "C" void kernel_launch(void* const* d_in, const int* in_sizes, int n_in,
                              void* d_out, int out_size, void* d_ws, size_t ws_size,
                              hipStream_t stream) {
    const float* desc_emb = (const float*)d_in[0];
    const float* nve      = (const float*)d_in[1];
    const float* Wg  = (const float*)d_in[2];
    const float* bg  = (const float*)d_in[3];
    const float* Wq  = (const float*)d_in[4];
    const float* bq  = (const float*)d_in[5];
    const float* Wk  = (const float*)d_in[6];
    const float* bk  = (const float*)d_in[7];
    const float* Wv  = (const float*)d_in[8];
    const float* bv_in = (const float*)d_in[9];
    const float* We1 = (const float*)d_in[10];
    const float* be1 = (const float*)d_in[11];
    const float* lng = (const float*)d_in[12];
    const float* lnb = (const float*)d_in[13];
    const float* We2 = (const float*)d_in[14];
    const float* be2 = (const float*)d_in[15];
    const float* Wa  = (const float*)d_in[16];
    const float* ba  = (const float*)d_in[17];
    const float* Wo  = (const float*)d_in[18];
    const float* bo  = (const float*)d_in[19];
    const float* tb  = (const float*)d_in[20];

    float* ws    = (float*)d_ws;
    float* desc  = ws + OFF_DESC;
    float* descT = ws + OFF_DESCT;
    float* U     = ws + OFF_U;
    float* VT    = ws + OFF_VT;
    float* varT  = ws + OFF_VART;
    float* vbuf  = ws + OFF_VBUF;
    float* sq    = ws + OFF_SQ;
    float* sk    = ws + OFF_SK;
    float* ctx   = ws + OFF_CTX;
    float* WgT   = ws + OFF_WGT;
    float* We1aT = ws + OFF_WE1AT;
    float* We1bT = ws + OFF_WE1BT;
    float* WvT   = ws + OFF_WVT;
    float* WoT   = ws + OFF_WOT;
    float* CuT   = ws + OFF_CUT;
    float* CvT   = ws + OFF_CVT;
    float* bu    = ws + OFF_BU;
    float* bv    = ws + OFF_BV;
    float* wqf   = ws + OFF_WQF;
    float* wkf   = ws + OFF_WKF;
    float* cvec  = ws + OFF_CVEC;
    float* rnd   = ws + OFF_RND;
    float* rnv   = ws + OFF_RNV;
    float* PKg   = ws + OFF_PKG;
    float* PKm   = ws + OFF_PKM;

    float* out = (float*)d_out;                  // [B][NS][D]
    float* aw  = out + (size_t)BB * NSS * DD;    // [B][H][NS][NS]

    prep_a<<<89, 256, 0, stream>>>(Wg, We1, Wv, Wo, Wq, bq, Wk, bk, We2, be2,
                                   Wa, lng, lnb,
                                   WgT, We1aT, We1bT, WvT, WoT,
                                   wqf, wkf, PKg, PKm, cvec);
    prep_b<<<34, 256, 0, stream>>>(WgT, We1aT, We1bT, bg, be1, CuT, CvT, bu, bv);
    proj_kernel<<<1318, 256, 0, stream>>>(desc_emb, nve, WgT, CuT, CvT, WvT,
                                          bg, bu, bv, bv_in, wqf, wkf, cvec,
                                          desc, descT, U, VT, varT, vbuf,
                                          sq, sk, rnd, rnv);
    se_attn_kernel<<<544, 256, 0, stream>>>(desc, descT, nve, varT, U, VT,
                                            vbuf, rnd, rnv, sq, sk,
                                            PKg, PKm, cvec, ba, tb, aw, ctx);
    outgemm_kernel<<<260, 256, 0, stream>>>(ctx, WoT, bo, out);
}